// Round 4
// baseline (294.163 us; speedup 1.0000x reference)
//
#include <hip/hip_runtime.h>
#include <hip/hip_bf16.h>
#include <stdint.h>

// Problem: N=512, R=4, B=65536, OUT=512
// out = relu(x @ W + b1) @ W2 + b2,  W = krylov_recon(G,H) (512x512)

typedef __attribute__((ext_vector_type(8))) short bf16x8;   // MFMA A/B frag (4 VGPR)
typedef __attribute__((ext_vector_type(4))) float f32x4;    // MFMA C/D frag
typedef __attribute__((ext_vector_type(4))) unsigned int u32x4;

__device__ __forceinline__ unsigned short f2bf(float f) {
  return __builtin_bit_cast(unsigned short, __float2bfloat16(f));
}

// ---------------------------------------------------------------------------
// Kernel 1: W partials.  W[a,b] = sum_i sum_j G[(a-j)&511,i]*sgn(b+j)*H[(b+j)&511,i]
// ---------------------------------------------------------------------------
__global__ void build_w_partials(const float* __restrict__ G, const float* __restrict__ H,
                                 float* __restrict__ Wp) {
  __shared__ float4 Gs[512];
  __shared__ float4 Hs[512];
  const int t = threadIdx.x;  // 256
  const float4* G4 = (const float4*)G;
  const float4* H4 = (const float4*)H;
  for (int i = t; i < 512; i += 256) { Gs[i] = G4[i]; Hs[i] = H4[i]; }
  __syncthreads();

  const int blk  = blockIdx.x;      // 0..255
  const int tile = blk >> 2;
  const int jc   = blk & 3;
  const int a0 = (tile >> 3) << 6;
  const int b0 = (tile & 7) << 6;
  const int ab = a0 + ((t >> 4) << 2);
  const int bb = b0 + ((t & 15) << 2);

  float acc[4][4] = {};
  const int j0 = jc << 7;
  for (int jj = 0; jj < 128; ++jj) {
    const int j = j0 + jj;
    float4 Ga[4], Hb[4];
#pragma unroll
    for (int r = 0; r < 4; ++r) Ga[r] = Gs[(ab + r - j) & 511];
#pragma unroll
    for (int c = 0; c < 4; ++c) {
      const int idx = bb + c + j;
      const float s = (idx >= 512) ? -1.f : 1.f;
      const float4 hv = Hs[idx & 511];
      Hb[c].x = hv.x * s; Hb[c].y = hv.y * s; Hb[c].z = hv.z * s; Hb[c].w = hv.w * s;
    }
#pragma unroll
    for (int r = 0; r < 4; ++r)
#pragma unroll
      for (int c = 0; c < 4; ++c)
        acc[r][c] += Ga[r].x * Hb[c].x + Ga[r].y * Hb[c].y +
                     Ga[r].z * Hb[c].z + Ga[r].w * Hb[c].w;
  }

  float* outp = Wp + (size_t)jc * 262144;
#pragma unroll
  for (int r = 0; r < 4; ++r)
#pragma unroll
    for (int c = 0; c < 4; ++c)
      outp[(size_t)(ab + r) * 512 + (bb + c)] = acc[r][c];
}

// ---------------------------------------------------------------------------
// Kernel 2: reduce 4 partials, store W transposed bf16: Wt[n=b][k=a]
// ---------------------------------------------------------------------------
__global__ void reduce_transpose_w(const float* __restrict__ Wp, unsigned short* __restrict__ Wt) {
  const int idx = blockIdx.x * 256 + threadIdx.x;
  const int b = idx >> 9, a = idx & 511;
  const size_t o = (size_t)a * 512 + b;
  float s = Wp[o] + Wp[o + 262144] + Wp[o + 524288] + Wp[o + 786432];
  Wt[(size_t)b * 512 + a] = f2bf(s);
}

// ---------------------------------------------------------------------------
// Kernel 3: W2 (512x512 f32 [k][n]) -> W2t bf16 [n][k]
// ---------------------------------------------------------------------------
__global__ void transpose_convert_w2(const float* __restrict__ W2, unsigned short* __restrict__ W2t) {
  const int idx = blockIdx.x * 256 + threadIdx.x;
  const int n = idx >> 9, k = idx & 511;
  W2t[(size_t)n * 512 + k] = f2bf(W2[(size_t)k * 512 + n]);
}

// ---------------------------------------------------------------------------
// Fused MLP: per block, out[64 x 512] = relu(x_tile @ Wt^T + b1) @ W2t^T + b2.
// 8 waves; each owns a 64-col slice (4 ni frags), all share the 64 rows
// (4 mi frags). 16x16x32 bf16 MFMA, acc 4x4.
//
// Phase A (barrier-free, LDS-free): each lane loads its own x A-frag as f32
//   directly from global (8 KB tile -> L1-served after first wave; HBM traffic
//   stays compulsory), converts via v_cvt_pk_bf16_f32 (RNE); B-frags stream
//   from L2-resident Wt. Fully unrolled; compiler schedules.
// h (64x512 bf16 = 64 KB) kept in LDS with XOR chunk swizzle (bijective).
// ONE __syncthreads() total. Phase B (barrier-free): h ds_reads + W2t from L2.
// LDS = 64 KB -> 2 blocks/CU target.
// ---------------------------------------------------------------------------
__global__ __launch_bounds__(512, 2) void mlp_fused(
    const float* __restrict__ x, const unsigned short* __restrict__ Wt,
    const unsigned short* __restrict__ W2t,
    const float* __restrict__ b1, const float* __restrict__ b2,
    float* __restrict__ out) {
  __shared__ __attribute__((aligned(16))) char lds[65536];  // h only

  const int tid  = threadIdx.x;
  const int lane = tid & 63;
  const int w    = tid >> 6;      // 0..7 = wave's 64-col group
  const int lr   = lane & 15;
  const int lq   = lane >> 4;     // 0..3
  const int m0   = (int)blockIdx.x << 6;

  // per-lane x row pointers (A-frag source): row = mi*16+lr, k base = lq*8
  const float* xp[4];
#pragma unroll
  for (int mi = 0; mi < 4; ++mi)
    xp[mi] = x + (size_t)(m0 + mi * 16 + lr) * 512 + (lq << 3);

  // B-frag pointers ([n][k] bf16, L2-resident): n = w*64+ni*16+lr, k byte = lq*16
  const char* pB1[4];
  const char* pB2[4];
#pragma unroll
  for (int ni = 0; ni < 4; ++ni) {
    const int n = w * 64 + ni * 16 + lr;
    pB1[ni] = (const char*)Wt  + (size_t)n * 1024 + (lq << 4);
    pB2[ni] = (const char*)W2t + (size_t)n * 1024 + (lq << 4);
  }

  float b1v[4], b2v[4];
#pragma unroll
  for (int ni = 0; ni < 4; ++ni) {
    b1v[ni] = b1[w * 64 + ni * 16 + lr];
    b2v[ni] = b2[w * 64 + ni * 16 + lr];
  }

  f32x4 acc[4][4];
  const f32x4 vz = {0.f, 0.f, 0.f, 0.f};
#pragma unroll
  for (int i = 0; i < 4; ++i)
#pragma unroll
    for (int j = 0; j < 4; ++j) acc[i][j] = vz;

  // ================= Phase A: h = relu(x @ Wt^T + b1) =================
#pragma unroll
  for (int t = 0; t < 16; ++t) {
    bf16x8 bfr[4];
#pragma unroll
    for (int ni = 0; ni < 4; ++ni)
      bfr[ni] = *(const bf16x8*)(pB1[ni] + (t << 6));
    bf16x8 afr[4];
#pragma unroll
    for (int mi = 0; mi < 4; ++mi) {
      const f32x4 lo = *(const f32x4*)(xp[mi] + (t << 5));
      const f32x4 hi = *(const f32x4*)(xp[mi] + (t << 5) + 4);
      unsigned int w0, w1, w2, w3;  // RNE f32->bf16 pack
      asm("v_cvt_pk_bf16_f32 %0, %1, %2" : "=v"(w0) : "v"(lo.x), "v"(lo.y));
      asm("v_cvt_pk_bf16_f32 %0, %1, %2" : "=v"(w1) : "v"(lo.z), "v"(lo.w));
      asm("v_cvt_pk_bf16_f32 %0, %1, %2" : "=v"(w2) : "v"(hi.x), "v"(hi.y));
      asm("v_cvt_pk_bf16_f32 %0, %1, %2" : "=v"(w3) : "v"(hi.z), "v"(hi.w));
      u32x4 pw = {w0, w1, w2, w3};
      afr[mi] = __builtin_bit_cast(bf16x8, pw);
    }
    __builtin_amdgcn_s_setprio(1);
#pragma unroll
    for (int mi = 0; mi < 4; ++mi)
#pragma unroll
      for (int ni = 0; ni < 4; ++ni)
        acc[mi][ni] = __builtin_amdgcn_mfma_f32_16x16x32_bf16(afr[mi], bfr[ni], acc[mi][ni], 0, 0, 0);
    __builtin_amdgcn_s_setprio(0);
  }

  // ---- epilogue A: bias+relu+cvt, swizzled h store (C/D: col=lr, row=lq*4+i)
  // h[r][col] at byte HBASE-free addr: r*1024 + ((chunk ^ (r&7))<<4) + (byte&15),
  // chunk = col*2 >> 4. Bijective per row.
#pragma unroll
  for (int mi = 0; mi < 4; ++mi)
#pragma unroll
    for (int ni = 0; ni < 4; ++ni)
#pragma unroll
      for (int i = 0; i < 4; ++i) {
        float v = acc[mi][ni][i] + b1v[ni];
        v = v > 0.f ? v : 0.f;
        const int r  = mi * 16 + lq * 4 + i;
        const int cb = (w * 64 + ni * 16 + lr) * 2;
        const unsigned addr = (unsigned)(r * 1024 + (((cb >> 4) ^ (r & 7)) << 4) + (cb & 15));
        *(unsigned short*)(lds + addr) = f2bf(v);
      }
  __syncthreads();   // the ONLY barrier: h fully written & visible

  // ================= Phase B: out = h @ W2t^T + b2 (barrier-free) =================
#pragma unroll
  for (int i = 0; i < 4; ++i)
#pragma unroll
    for (int j = 0; j < 4; ++j) acc[i][j] = vz;

#pragma unroll
  for (int t = 0; t < 16; ++t) {
    bf16x8 bfr[4];
#pragma unroll
    for (int ni = 0; ni < 4; ++ni)
      bfr[ni] = *(const bf16x8*)(pB2[ni] + (t << 6));
    bf16x8 afr[4];
#pragma unroll
    for (int mi = 0; mi < 4; ++mi) {
      const int r = mi * 16 + lr;
      const int cidx = t * 4 + lq;               // 16B chunk of row r
      afr[mi] = *(const bf16x8*)(lds + r * 1024 + ((cidx ^ (r & 7)) << 4));
    }
    __builtin_amdgcn_s_setprio(1);
#pragma unroll
    for (int mi = 0; mi < 4; ++mi)
#pragma unroll
      for (int ni = 0; ni < 4; ++ni)
        acc[mi][ni] = __builtin_amdgcn_mfma_f32_16x16x32_bf16(afr[mi], bfr[ni], acc[mi][ni], 0, 0, 0);
    __builtin_amdgcn_s_setprio(0);
  }

  // ---- epilogue B: f32 out writes ----
#pragma unroll
  for (int mi = 0; mi < 4; ++mi)
#pragma unroll
    for (int ni = 0; ni < 4; ++ni)
#pragma unroll
      for (int i = 0; i < 4; ++i)
        out[(size_t)(m0 + mi * 16 + lq * 4 + i) * 512 + w * 64 + ni * 16 + lr] =
            acc[mi][ni][i] + b2v[ni];
}

// ---------------------------------------------------------------------------
extern "C" void kernel_launch(void* const* d_in, const int* in_sizes, int n_in,
                              void* d_out, int out_size, void* d_ws, size_t ws_size,
                              hipStream_t stream) {
  (void)in_sizes; (void)n_in; (void)out_size; (void)ws_size;
  const float* x  = (const float*)d_in[0];  // (65536, 512)
  const float* G  = (const float*)d_in[1];  // (512, 4)
  const float* H  = (const float*)d_in[2];  // (512, 4)
  const float* b1 = (const float*)d_in[3];  // (512,)
  const float* W2 = (const float*)d_in[4];  // (512, 512)
  const float* b2 = (const float*)d_in[5];  // (512,)
  float* out = (float*)d_out;               // (65536, 512) f32

  char* ws = (char*)d_ws;                                  // ~5.2 MB used
  unsigned short* Wt  = (unsigned short*)ws;               //   524,288 B
  unsigned short* W2t = (unsigned short*)(ws + 524288);    //   524,288 B
  float*          Wp  = (float*)(ws + 1048576);            // 4,194,304 B

  build_w_partials<<<256, 256, 0, stream>>>(G, H, Wp);
  reduce_transpose_w<<<1024, 256, 0, stream>>>(Wp, Wt);
  transpose_convert_w2<<<1024, 256, 0, stream>>>(W2, W2t);
  mlp_fused<<<1024, 512, 0, stream>>>(x, Wt, W2t, b1, b2, out);
}

// Round 5
// 174.585 us; speedup vs baseline: 1.6849x; 1.6849x over previous
//
#include <hip/hip_runtime.h>
#include <hip/hip_bf16.h>
#include <stdint.h>

// Problem: N=512, R=4, B=65536, OUT=512
// out = relu(x @ W + b1) @ W2 + b2,  W = krylov_recon(G,H) (512x512)

typedef __attribute__((ext_vector_type(8))) short bf16x8;   // MFMA A/B frag (4 VGPR)
typedef __attribute__((ext_vector_type(4))) float f32x4;    // MFMA C/D frag
typedef __attribute__((ext_vector_type(4))) unsigned int u32x4;

__device__ __forceinline__ unsigned short f2bf(float f) {
  return __builtin_bit_cast(unsigned short, __float2bfloat16(f));
}

// ---------------------------------------------------------------------------
// Kernel 1: W partials.  W[a,b] = sum_i sum_j G[(a-j)&511,i]*sgn(b+j)*H[(b+j)&511,i]
// ---------------------------------------------------------------------------
__global__ void build_w_partials(const float* __restrict__ G, const float* __restrict__ H,
                                 float* __restrict__ Wp) {
  __shared__ float4 Gs[512];
  __shared__ float4 Hs[512];
  const int t = threadIdx.x;  // 256
  const float4* G4 = (const float4*)G;
  const float4* H4 = (const float4*)H;
  for (int i = t; i < 512; i += 256) { Gs[i] = G4[i]; Hs[i] = H4[i]; }
  __syncthreads();

  const int blk  = blockIdx.x;      // 0..255
  const int tile = blk >> 2;
  const int jc   = blk & 3;
  const int a0 = (tile >> 3) << 6;
  const int b0 = (tile & 7) << 6;
  const int ab = a0 + ((t >> 4) << 2);
  const int bb = b0 + ((t & 15) << 2);

  float acc[4][4] = {};
  const int j0 = jc << 7;
  for (int jj = 0; jj < 128; ++jj) {
    const int j = j0 + jj;
    float4 Ga[4], Hb[4];
#pragma unroll
    for (int r = 0; r < 4; ++r) Ga[r] = Gs[(ab + r - j) & 511];
#pragma unroll
    for (int c = 0; c < 4; ++c) {
      const int idx = bb + c + j;
      const float s = (idx >= 512) ? -1.f : 1.f;
      const float4 hv = Hs[idx & 511];
      Hb[c].x = hv.x * s; Hb[c].y = hv.y * s; Hb[c].z = hv.z * s; Hb[c].w = hv.w * s;
    }
#pragma unroll
    for (int r = 0; r < 4; ++r)
#pragma unroll
      for (int c = 0; c < 4; ++c)
        acc[r][c] += Ga[r].x * Hb[c].x + Ga[r].y * Hb[c].y +
                     Ga[r].z * Hb[c].z + Ga[r].w * Hb[c].w;
  }

  float* outp = Wp + (size_t)jc * 262144;
#pragma unroll
  for (int r = 0; r < 4; ++r)
#pragma unroll
    for (int c = 0; c < 4; ++c)
      outp[(size_t)(ab + r) * 512 + (bb + c)] = acc[r][c];
}

// ---------------------------------------------------------------------------
// Kernel 2: reduce 4 partials, store W transposed bf16: Wt[n=b][k=a]
// ---------------------------------------------------------------------------
__global__ void reduce_transpose_w(const float* __restrict__ Wp, unsigned short* __restrict__ Wt) {
  const int idx = blockIdx.x * 256 + threadIdx.x;
  const int b = idx >> 9, a = idx & 511;
  const size_t o = (size_t)a * 512 + b;
  float s = Wp[o] + Wp[o + 262144] + Wp[o + 524288] + Wp[o + 786432];
  Wt[(size_t)b * 512 + a] = f2bf(s);
}

// ---------------------------------------------------------------------------
// Kernel 3: W2 (512x512 f32 [k][n]) -> W2t bf16 [n][k]
// ---------------------------------------------------------------------------
__global__ void transpose_convert_w2(const float* __restrict__ W2, unsigned short* __restrict__ W2t) {
  const int idx = blockIdx.x * 256 + threadIdx.x;
  const int n = idx >> 9, k = idx & 511;
  W2t[(size_t)n * 512 + k] = f2bf(W2[(size_t)k * 512 + n]);
}

// ---------------------------------------------------------------------------
// Pipelined GEMM: C[M x 512] = epi(A[M x 512] @ Bt^T + bias)
// BM=BN=256, BK=32, NT=16. 8 waves (2M x 4N), per-wave 128x64 out (acc 8x4).
// 3-slot LDS tile ring, prefetch distance 2 (slot(t+2)=slot(t-1), consumed),
// ONE counted vmcnt per K-tile (6 for AF32, 4 for bf16), raw s_barrier pairs
// per phase, setprio around MFMA, sched_barrier after every wait (rule 18).
// LDS bank-audited <=2-way: f32 rows chunk^=(r&7); bf16 64B rows row-pair
// layout (r>>1)*128+(r&1)*64+((c^((r>>1)&3))<<4). gll = linear dest +
// inverse-swizzled global source (round-trip verified).
// AF32: A=x f32 (cvt in-reg after lgkmcnt), epilogue relu+bf16. else f32 out.
// ---------------------------------------------------------------------------
template <bool AF32>
__global__ __launch_bounds__(512, 2) void gemm_pipe(
    const void* __restrict__ Ap, const unsigned short* __restrict__ Bt,
    const float* __restrict__ bias, void* __restrict__ Cp) {
  constexpr int NT    = 16;
  constexpr int AHALF = AF32 ? 16384 : 8192;   // 128 rows x 32k x {4,2}B
  constexpr int BHALF = 8192;
  constexpr int SLOT  = 2 * AHALF + 2 * BHALF; // 48K / 32K
  constexpr int NAG   = AF32 ? 2 : 1;          // A glls per half per thread

  __shared__ __attribute__((aligned(16))) char lds[3 * SLOT];

  const int tid  = threadIdx.x;
  const int lane = tid & 63;
  const int w    = tid >> 6;          // 0..7
  const int wm   = w & 1;             // A half owner
  const int wn   = w >> 1;            // 0..3 -> B half = wn>>1
  const int lr   = lane & 15;
  const int lq   = lane >> 4;

  const int bid = (int)blockIdx.x;                // 512 blocks
  const int wg  = (bid & 7) * 64 + (bid >> 3);    // XCD-bijective (512%8==0)
  const int m0  = (wg >> 1) << 8;
  const int n0  = (wg & 1) << 8;

  // ---- bias first; drain so the vm FIFO holds ONLY staging glls ----
  float bv[4];
#pragma unroll
  for (int ni = 0; ni < 4; ++ni) bv[ni] = bias[n0 + wn * 64 + ni * 16 + lr];
  asm volatile("s_waitcnt vmcnt(0)" ::: "memory");

  // ---- staging source offsets (inverse-swizzled) ----
  // A (AF32): c_lin = i*512+tid; row=c_lin>>3; cr=c_lin&7; 128B f32 rows.
  // A (bf16) & B: c_lin=tid; row'=c_lin>>3; sub=c_lin&7; r=2row'+(sub>>2);
  //               cg=(sub&3)^(row'&3); 64B rows, row-pair layout.
  size_t aOff[NAG];
  if constexpr (AF32) {
#pragma unroll
    for (int i = 0; i < 2; ++i) {
      const int c = i * 512 + tid, row = c >> 3, cr = c & 7;
      aOff[i] = (size_t)row * 2048 + (size_t)((cr ^ (row & 7)) << 4);
    }
  } else {
    const int rp = tid >> 3, sub = tid & 7;
    const int r = 2 * rp + (sub >> 2), cg = (sub & 3) ^ (rp & 3);
    aOff[0] = (size_t)r * 1024 + (size_t)(cg << 4);
  }
  size_t bOff;
  {
    const int rp = tid >> 3, sub = tid & 7;
    const int r = 2 * rp + (sub >> 2), cg = (sub & 3) ^ (rp & 3);
    bOff = (size_t)r * 1024 + (size_t)(cg << 4);
  }
  const char* aBase = (const char*)Ap + (size_t)m0 * (AF32 ? 2048 : 1024);
  const char* bBase = (const char*)Bt + (size_t)n0 * 1024;

  auto stageA = [&](int kt, int sl, int h) {
#pragma unroll
    for (int i = 0; i < NAG; ++i)
      __builtin_amdgcn_global_load_lds(
        (const __attribute__((address_space(1))) void*)
          (aBase + (size_t)h * 128 * (AF32 ? 2048 : 1024) + (size_t)kt * (AF32 ? 128 : 64) + aOff[i]),
        (__attribute__((address_space(3))) void*)(lds + sl * SLOT + h * AHALF + i * 8192 + w * 1024),
        16, 0, 0);
  };
  auto stageB = [&](int kt, int sl, int h) {
    __builtin_amdgcn_global_load_lds(
      (const __attribute__((address_space(1))) void*)
        (bBase + (size_t)h * 131072 + (size_t)kt * 64 + bOff),
      (__attribute__((address_space(3))) void*)(lds + sl * SLOT + 2 * AHALF + h * BHALF + w * 1024),
      16, 0, 0);
  };

  // ---- ds_read frag offsets (bank-audited 2-way max) ----
  int offA8[8], offB4[4];
#pragma unroll
  for (int mi = 0; mi < 8; ++mi) {
    const int r = mi * 16 + lr;
    if constexpr (AF32)
      offA8[mi] = r * 128 + (((2 * lq) ^ (r & 7)) << 4);       // j=1 => ^16
    else
      offA8[mi] = (r >> 1) * 128 + (r & 1) * 64 + ((lq ^ ((r >> 1) & 3)) << 4);
  }
#pragma unroll
  for (int ni = 0; ni < 4; ++ni) {
    const int rb = (wn & 1) * 64 + ni * 16 + lr;
    offB4[ni] = (rb >> 1) * 128 + (rb & 1) * 64 + ((lq ^ ((rb >> 1) & 3)) << 4);
  }

  f32x4 acc[8][4];
  const f32x4 vz = {0.f, 0.f, 0.f, 0.f};
#pragma unroll
  for (int i = 0; i < 8; ++i)
#pragma unroll
    for (int j = 0; j < 4; ++j) acc[i][j] = vz;

  // ---- prologue: tiles 0,1 fully staged; wait tile 0 landed ----
  stageA(0, 0, 0); stageA(0, 0, 1); stageB(0, 0, 0); stageB(0, 0, 1);
  stageA(1, 1, 0); stageA(1, 1, 1); stageB(1, 1, 0); stageB(1, 1, 1);
  if constexpr (AF32) asm volatile("s_waitcnt vmcnt(6)" ::: "memory");
  else                asm volatile("s_waitcnt vmcnt(4)" ::: "memory");
  __builtin_amdgcn_s_barrier();
  __builtin_amdgcn_sched_barrier(0);

  for (int t = 0; t < NT; ++t) {
    const int s  = t % 3;
    const int s2 = (t + 2) % 3;       // slot of tile t-1 (fully consumed)
    const char* aB = lds + s * SLOT + wm * AHALF;
    const char* bB = lds + s * SLOT + 2 * AHALF + (wn >> 1) * BHALF;
    bf16x8 bfr[4];

    // ================= phase 0 (mi 0..3) =================
    {
#pragma unroll
      for (int ni = 0; ni < 4; ++ni) bfr[ni] = *(const bf16x8*)(bB + offB4[ni]);
      bf16x8 afr[4];
      f32x4 lo[4], hi[4];
      if constexpr (AF32) {
#pragma unroll
        for (int k = 0; k < 4; ++k) {
          lo[k] = *(const f32x4*)(aB + offA8[k]);
          hi[k] = *(const f32x4*)(aB + (offA8[k] ^ 16));
        }
      } else {
#pragma unroll
        for (int k = 0; k < 4; ++k) afr[k] = *(const bf16x8*)(aB + offA8[k]);
      }
      if (t + 2 < NT) { stageA(t + 2, s2, 0); stageB(t + 2, s2, 0); }
      __builtin_amdgcn_s_barrier();
      asm volatile("s_waitcnt lgkmcnt(0)" ::: "memory");
      __builtin_amdgcn_sched_barrier(0);
      if constexpr (AF32) {
#pragma unroll
        for (int k = 0; k < 4; ++k) {
          unsigned int w0, w1, w2, w3;
          asm("v_cvt_pk_bf16_f32 %0, %1, %2" : "=v"(w0) : "v"(lo[k].x), "v"(lo[k].y));
          asm("v_cvt_pk_bf16_f32 %0, %1, %2" : "=v"(w1) : "v"(lo[k].z), "v"(lo[k].w));
          asm("v_cvt_pk_bf16_f32 %0, %1, %2" : "=v"(w2) : "v"(hi[k].x), "v"(hi[k].y));
          asm("v_cvt_pk_bf16_f32 %0, %1, %2" : "=v"(w3) : "v"(hi[k].z), "v"(hi[k].w));
          u32x4 pw = {w0, w1, w2, w3};
          afr[k] = __builtin_bit_cast(bf16x8, pw);
        }
      }
      __builtin_amdgcn_s_setprio(1);
#pragma unroll
      for (int k = 0; k < 4; ++k)
#pragma unroll
        for (int ni = 0; ni < 4; ++ni)
          acc[k][ni] = __builtin_amdgcn_mfma_f32_16x16x32_bf16(afr[k], bfr[ni], acc[k][ni], 0, 0, 0);
      __builtin_amdgcn_s_setprio(0);
      __builtin_amdgcn_s_barrier();
      __builtin_amdgcn_sched_barrier(0);
    }

    // ================= phase 1 (mi 4..7) =================
    {
      bf16x8 afr[4];
      f32x4 lo[4], hi[4];
      if constexpr (AF32) {
#pragma unroll
        for (int k = 0; k < 4; ++k) {
          lo[k] = *(const f32x4*)(aB + offA8[4 + k]);
          hi[k] = *(const f32x4*)(aB + (offA8[4 + k] ^ 16));
        }
      } else {
#pragma unroll
        for (int k = 0; k < 4; ++k) afr[k] = *(const bf16x8*)(aB + offA8[4 + k]);
      }
      if (t + 2 < NT) { stageA(t + 2, s2, 1); stageB(t + 2, s2, 1); }
      __builtin_amdgcn_s_barrier();
      asm volatile("s_waitcnt lgkmcnt(0)" ::: "memory");
      __builtin_amdgcn_sched_barrier(0);
      if constexpr (AF32) {
#pragma unroll
        for (int k = 0; k < 4; ++k) {
          unsigned int w0, w1, w2, w3;
          asm("v_cvt_pk_bf16_f32 %0, %1, %2" : "=v"(w0) : "v"(lo[k].x), "v"(lo[k].y));
          asm("v_cvt_pk_bf16_f32 %0, %1, %2" : "=v"(w1) : "v"(lo[k].z), "v"(lo[k].w));
          asm("v_cvt_pk_bf16_f32 %0, %1, %2" : "=v"(w2) : "v"(hi[k].x), "v"(hi[k].y));
          asm("v_cvt_pk_bf16_f32 %0, %1, %2" : "=v"(w3) : "v"(hi[k].z), "v"(hi[k].w));
          u32x4 pw = {w0, w1, w2, w3};
          afr[k] = __builtin_bit_cast(bf16x8, pw);
        }
      }
      __builtin_amdgcn_s_setprio(1);
#pragma unroll
      for (int k = 0; k < 4; ++k)
#pragma unroll
        for (int ni = 0; ni < 4; ++ni)
          acc[4 + k][ni] = __builtin_amdgcn_mfma_f32_16x16x32_bf16(afr[k], bfr[ni], acc[4 + k][ni], 0, 0, 0);
      __builtin_amdgcn_s_setprio(0);
      // boundary: tile t+1 glls done; keep t+2's (GPT) in flight
      if (t < NT - 2) {
        if constexpr (AF32) asm volatile("s_waitcnt vmcnt(6)" ::: "memory");
        else                asm volatile("s_waitcnt vmcnt(4)" ::: "memory");
      } else if (t == NT - 2) {
        asm volatile("s_waitcnt vmcnt(0)" ::: "memory");
      }
      __builtin_amdgcn_s_barrier();
      __builtin_amdgcn_sched_barrier(0);
    }
  }

  // ---- epilogue: C/D col=lr, row=lq*4+i ----
#pragma unroll
  for (int ni = 0; ni < 4; ++ni) {
    const int gc = n0 + wn * 64 + ni * 16 + lr;
#pragma unroll
    for (int mi = 0; mi < 8; ++mi) {
      const int gr = m0 + wm * 128 + mi * 16 + lq * 4;
      const f32x4 v = acc[mi][ni];
#pragma unroll
      for (int i = 0; i < 4; ++i) {
        const float val = v[i] + bv[ni];
        if constexpr (AF32)
          ((unsigned short*)Cp)[(size_t)(gr + i) * 512 + gc] = f2bf(val > 0.f ? val : 0.f);
        else
          ((float*)Cp)[(size_t)(gr + i) * 512 + gc] = val;
      }
    }
  }
}

// ---------------------------------------------------------------------------
extern "C" void kernel_launch(void* const* d_in, const int* in_sizes, int n_in,
                              void* d_out, int out_size, void* d_ws, size_t ws_size,
                              hipStream_t stream) {
  (void)in_sizes; (void)n_in; (void)out_size; (void)ws_size;
  const float* x  = (const float*)d_in[0];  // (65536, 512)
  const float* G  = (const float*)d_in[1];  // (512, 4)
  const float* H  = (const float*)d_in[2];  // (512, 4)
  const float* b1 = (const float*)d_in[3];  // (512,)
  const float* W2 = (const float*)d_in[4];  // (512, 512)
  const float* b2 = (const float*)d_in[5];  // (512,)
  float* out = (float*)d_out;               // (65536, 512) f32

  char* ws = (char*)d_ws;                                    // ~72.4 MB
  unsigned short* h   = (unsigned short*)ws;                 // 67,108,864 B
  unsigned short* Wt  = (unsigned short*)(ws + 67108864);    //    524,288 B
  unsigned short* W2t = (unsigned short*)(ws + 67633152);    //    524,288 B
  float*          Wp  = (float*)(ws + 68157440);             //  4,194,304 B

  build_w_partials<<<256, 256, 0, stream>>>(G, H, Wp);
  reduce_transpose_w<<<1024, 256, 0, stream>>>(Wp, Wt);
  transpose_convert_w2<<<1024, 256, 0, stream>>>(W2, W2t);
  gemm_pipe<true><<<512, 512, 0, stream>>>((const void*)x, Wt, b1, (void*)h);
  gemm_pipe<false><<<512, 512, 0, stream>>>((const void*)h, W2t, b2, (void*)out);
}

// Round 6
// 168.708 us; speedup vs baseline: 1.7436x; 1.0348x over previous
//
#include <hip/hip_runtime.h>
#include <hip/hip_bf16.h>
#include <stdint.h>

// Problem: N=512, R=4, B=65536, OUT=512
// out = relu(x @ W + b1) @ W2 + b2,  W = krylov_recon(G,H) (512x512)

typedef __attribute__((ext_vector_type(8))) short bf16x8;   // MFMA A/B frag (4 VGPR)
typedef __attribute__((ext_vector_type(4))) float f32x4;    // MFMA C/D frag
typedef __attribute__((ext_vector_type(4))) unsigned int u32x4;

__device__ __forceinline__ unsigned short f2bf(float f) {
  return __builtin_bit_cast(unsigned short, __float2bfloat16(f));
}

// ---------------------------------------------------------------------------
// Kernel 1: W partials.  W[a,b] = sum_i sum_j G[(a-j)&511,i]*sgn(b+j)*H[(b+j)&511,i]
// ---------------------------------------------------------------------------
__global__ void build_w_partials(const float* __restrict__ G, const float* __restrict__ H,
                                 float* __restrict__ Wp) {
  __shared__ float4 Gs[512];
  __shared__ float4 Hs[512];
  const int t = threadIdx.x;  // 256
  const float4* G4 = (const float4*)G;
  const float4* H4 = (const float4*)H;
  for (int i = t; i < 512; i += 256) { Gs[i] = G4[i]; Hs[i] = H4[i]; }
  __syncthreads();

  const int blk  = blockIdx.x;      // 0..255
  const int tile = blk >> 2;
  const int jc   = blk & 3;
  const int a0 = (tile >> 3) << 6;
  const int b0 = (tile & 7) << 6;
  const int ab = a0 + ((t >> 4) << 2);
  const int bb = b0 + ((t & 15) << 2);

  float acc[4][4] = {};
  const int j0 = jc << 7;
  for (int jj = 0; jj < 128; ++jj) {
    const int j = j0 + jj;
    float4 Ga[4], Hb[4];
#pragma unroll
    for (int r = 0; r < 4; ++r) Ga[r] = Gs[(ab + r - j) & 511];
#pragma unroll
    for (int c = 0; c < 4; ++c) {
      const int idx = bb + c + j;
      const float s = (idx >= 512) ? -1.f : 1.f;
      const float4 hv = Hs[idx & 511];
      Hb[c].x = hv.x * s; Hb[c].y = hv.y * s; Hb[c].z = hv.z * s; Hb[c].w = hv.w * s;
    }
#pragma unroll
    for (int r = 0; r < 4; ++r)
#pragma unroll
      for (int c = 0; c < 4; ++c)
        acc[r][c] += Ga[r].x * Hb[c].x + Ga[r].y * Hb[c].y +
                     Ga[r].z * Hb[c].z + Ga[r].w * Hb[c].w;
  }

  float* outp = Wp + (size_t)jc * 262144;
#pragma unroll
  for (int r = 0; r < 4; ++r)
#pragma unroll
    for (int c = 0; c < 4; ++c)
      outp[(size_t)(ab + r) * 512 + (bb + c)] = acc[r][c];
}

// ---------------------------------------------------------------------------
// Kernel 2: reduce 4 partials, store W transposed bf16: Wt[n=b][k=a]
// ---------------------------------------------------------------------------
__global__ void reduce_transpose_w(const float* __restrict__ Wp, unsigned short* __restrict__ Wt) {
  const int idx = blockIdx.x * 256 + threadIdx.x;
  const int b = idx >> 9, a = idx & 511;
  const size_t o = (size_t)a * 512 + b;
  float s = Wp[o] + Wp[o + 262144] + Wp[o + 524288] + Wp[o + 786432];
  Wt[(size_t)b * 512 + a] = f2bf(s);
}

// ---------------------------------------------------------------------------
// Kernel 3: W2 (512x512 f32 [k][n]) -> W2t bf16 [n][k]
// ---------------------------------------------------------------------------
__global__ void transpose_convert_w2(const float* __restrict__ W2, unsigned short* __restrict__ W2t) {
  const int idx = blockIdx.x * 256 + threadIdx.x;
  const int n = idx >> 9, k = idx & 511;
  W2t[(size_t)n * 512 + k] = f2bf(W2[(size_t)k * 512 + n]);
}

// ---------------------------------------------------------------------------
// Pipelined GEMM: C[M x 512] = epi(A[M x 512] @ Bt^T + bias)
// BM=BN=256, BK=32, NT=16. 8 waves (2M x 4N), per-wave 128x64 (acc 8x4).
// 2 phases/tile (16 MFMA each), 4 barriers/tile, ONE counted vmcnt per tile.
// AF32 (GEMM1: A=x f32): A ring 3x32KB, B ring 3x16KB (144KB), prefetch
//   distance 2, gate vmcnt(6); cvt f32->bf16 in-reg after lgkmcnt.
// bf16 (GEMM2): A,B rings 4x16KB (128KB), distance 3, gate vmcnt(8).
// LDS swizzles (consecutive-8-lane conflict-free, verified granule perms):
//   f32 rows (128B):  byte = r*128 + ((c ^ (r&7))<<4)        c=0..7
//   bf16 rows (64B):  byte = r*64  + ((c ^ ((r>>1)&3))<<4)   c=0..3
// gll keeps linear LDS dest; the global SOURCE is inverse-permuted (rule 21).
// ---------------------------------------------------------------------------
template <bool AF32>
__global__ __launch_bounds__(512, 2) void gemm_pipe(
    const void* __restrict__ Ap, const unsigned short* __restrict__ Bt,
    const float* __restrict__ bias, void* __restrict__ Cp) {
  constexpr int NT    = 16;
  constexpr int ASLOT = AF32 ? 32768 : 16384;
  constexpr int ARING = AF32 ? 3 : 4;
  constexpr int BSLOT = 16384;
  constexpr int BRING = AF32 ? 3 : 4;
  constexpr int DIST  = AF32 ? 2 : 3;
  constexpr int NAG   = AF32 ? 4 : 2;      // A glls / thread / tile
  constexpr int BBASE = ARING * ASLOT;

  __shared__ __attribute__((aligned(16))) char lds[ARING * ASLOT + BRING * BSLOT];

  const int tid  = threadIdx.x;
  const int lane = tid & 63;
  const int w    = tid >> 6;          // 0..7
  const int wm   = w & 1;             // M half (128 rows)
  const int wn   = w >> 1;            // 0..3 (64 n-cols each)
  const int lr   = lane & 15;
  const int lq   = lane >> 4;

  const int bid = (int)blockIdx.x;                // 512 blocks
  const int wg  = (bid & 7) * 64 + (bid >> 3);    // XCD-bijective (512%8==0)
  const int m0  = (wg >> 1) << 8;
  const int n0  = (wg & 1) << 8;

  // ---- bias first; drain so the vm FIFO holds ONLY staging loads ----
  float bv[4];
#pragma unroll
  for (int ni = 0; ni < 4; ++ni) bv[ni] = bias[n0 + wn * 64 + ni * 16 + lr];
  asm volatile("s_waitcnt vmcnt(0)" ::: "memory");

  // ---- staging source offsets (inverse-permuted per 16B chunk) ----
  size_t aSrcOff[NAG];
  if constexpr (AF32) {
#pragma unroll
    for (int i = 0; i < 4; ++i) {
      const int r = i * 64 + (tid >> 3);          // 0..255
      const int s = tid & 7;
      const int c = s ^ (r & 7);
      aSrcOff[i] = (size_t)r * 2048 + (size_t)(c << 4);
    }
  } else {
#pragma unroll
    for (int i = 0; i < 2; ++i) {
      const int r = i * 128 + (tid >> 2);
      const int s = tid & 3;
      const int c = s ^ ((r >> 1) & 3);
      aSrcOff[i] = (size_t)r * 1024 + (size_t)(c << 4);
    }
  }
  size_t bSrcOff[2];
#pragma unroll
  for (int i = 0; i < 2; ++i) {
    const int r = i * 128 + (tid >> 2);
    const int s = tid & 3;
    const int c = s ^ ((r >> 1) & 3);
    bSrcOff[i] = (size_t)r * 1024 + (size_t)(c << 4);
  }
  const char* aBase = (const char*)Ap + (size_t)m0 * (AF32 ? 2048 : 1024);
  const char* bBase = (const char*)Bt + (size_t)n0 * 1024;

  auto stageA = [&](int kt) {
    const int sl = kt % ARING;
#pragma unroll
    for (int i = 0; i < NAG; ++i)
      __builtin_amdgcn_global_load_lds(
        (const __attribute__((address_space(1))) void*)
          (aBase + aSrcOff[i] + (size_t)kt * (AF32 ? 128 : 64)),
        (__attribute__((address_space(3))) void*)(lds + sl * ASLOT + i * 8192 + w * 1024),
        16, 0, 0);
  };
  auto stageB = [&](int kt) {
    const int sl = kt % BRING;
#pragma unroll
    for (int i = 0; i < 2; ++i)
      __builtin_amdgcn_global_load_lds(
        (const __attribute__((address_space(1))) void*)
          (bBase + bSrcOff[i] + (size_t)kt * 64),
        (__attribute__((address_space(3))) void*)(lds + BBASE + sl * BSLOT + i * 8192 + w * 1024),
        16, 0, 0);
  };

  // ---- frag ds_read offsets (conflict-free per consecutive-8 lanes) ----
  int offA[8], offB[4];
#pragma unroll
  for (int mi = 0; mi < 8; ++mi) {
    const int r = wm * 128 + mi * 16 + lr;
    if constexpr (AF32)
      offA[mi] = r * 128 + (((2 * lq) ^ (r & 7)) << 4);    // hi read = ^16
    else
      offA[mi] = r * 64 + ((lq ^ ((r >> 1) & 3)) << 4);
  }
#pragma unroll
  for (int ni = 0; ni < 4; ++ni) {
    const int rb = wn * 64 + ni * 16 + lr;
    offB[ni] = rb * 64 + ((lq ^ ((rb >> 1) & 3)) << 4);
  }

  f32x4 acc[8][4];
  const f32x4 vz = {0.f, 0.f, 0.f, 0.f};
#pragma unroll
  for (int i = 0; i < 8; ++i)
#pragma unroll
    for (int j = 0; j < 4; ++j) acc[i][j] = vz;

  // ---- prologue ----
  stageA(0); stageB(0); stageA(1); stageB(1);
  if constexpr (!AF32) { stageA(2); stageB(2); }
  if constexpr (AF32) asm volatile("s_waitcnt vmcnt(6)" ::: "memory");
  else                asm volatile("s_waitcnt vmcnt(8)" ::: "memory");
  __builtin_amdgcn_s_barrier();
  __builtin_amdgcn_sched_barrier(0);

#pragma unroll
  for (int t = 0; t < NT; ++t) {
    const char* aS = lds + (t % ARING) * ASLOT;
    const char* bS = lds + BBASE + (t % BRING) * BSLOT;
    bf16x8 bfr[4];

    // ============ phase 0: B frags + A mi0-3, stage A(t+DIST) ============
    {
#pragma unroll
      for (int ni = 0; ni < 4; ++ni) bfr[ni] = *(const bf16x8*)(bS + offB[ni]);
      bf16x8 afr[4];
      f32x4 lo[4], hi[4];
      if constexpr (AF32) {
#pragma unroll
        for (int k = 0; k < 4; ++k) {
          lo[k] = *(const f32x4*)(aS + offA[k]);
          hi[k] = *(const f32x4*)(aS + (offA[k] ^ 16));
        }
      } else {
#pragma unroll
        for (int k = 0; k < 4; ++k) afr[k] = *(const bf16x8*)(aS + offA[k]);
      }
      if (t + DIST < NT) stageA(t + DIST);
      __builtin_amdgcn_s_barrier();
      asm volatile("s_waitcnt lgkmcnt(0)" ::: "memory");
      __builtin_amdgcn_sched_barrier(0);
      if constexpr (AF32) {
#pragma unroll
        for (int k = 0; k < 4; ++k) {
          unsigned int w0, w1, w2, w3;
          asm("v_cvt_pk_bf16_f32 %0, %1, %2" : "=v"(w0) : "v"(lo[k].x), "v"(lo[k].y));
          asm("v_cvt_pk_bf16_f32 %0, %1, %2" : "=v"(w1) : "v"(lo[k].z), "v"(lo[k].w));
          asm("v_cvt_pk_bf16_f32 %0, %1, %2" : "=v"(w2) : "v"(hi[k].x), "v"(hi[k].y));
          asm("v_cvt_pk_bf16_f32 %0, %1, %2" : "=v"(w3) : "v"(hi[k].z), "v"(hi[k].w));
          u32x4 pw = {w0, w1, w2, w3};
          afr[k] = __builtin_bit_cast(bf16x8, pw);
        }
      }
      __builtin_amdgcn_s_setprio(1);
#pragma unroll
      for (int k = 0; k < 4; ++k)
#pragma unroll
        for (int ni = 0; ni < 4; ++ni)
          acc[k][ni] = __builtin_amdgcn_mfma_f32_16x16x32_bf16(afr[k], bfr[ni], acc[k][ni], 0, 0, 0);
      __builtin_amdgcn_s_setprio(0);
      __builtin_amdgcn_s_barrier();
      __builtin_amdgcn_sched_barrier(0);
    }

    // ============ phase 1: A mi4-7, stage B(t+DIST), gated vmcnt ============
    {
      bf16x8 afr[4];
      f32x4 lo[4], hi[4];
      if constexpr (AF32) {
#pragma unroll
        for (int k = 0; k < 4; ++k) {
          lo[k] = *(const f32x4*)(aS + offA[4 + k]);
          hi[k] = *(const f32x4*)(aS + (offA[4 + k] ^ 16));
        }
      } else {
#pragma unroll
        for (int k = 0; k < 4; ++k) afr[k] = *(const bf16x8*)(aS + offA[4 + k]);
      }
      if (t + DIST < NT) stageB(t + DIST);
      __builtin_amdgcn_s_barrier();
      asm volatile("s_waitcnt lgkmcnt(0)" ::: "memory");
      __builtin_amdgcn_sched_barrier(0);
      if constexpr (AF32) {
#pragma unroll
        for (int k = 0; k < 4; ++k) {
          unsigned int w0, w1, w2, w3;
          asm("v_cvt_pk_bf16_f32 %0, %1, %2" : "=v"(w0) : "v"(lo[k].x), "v"(lo[k].y));
          asm("v_cvt_pk_bf16_f32 %0, %1, %2" : "=v"(w1) : "v"(lo[k].z), "v"(lo[k].w));
          asm("v_cvt_pk_bf16_f32 %0, %1, %2" : "=v"(w2) : "v"(hi[k].x), "v"(hi[k].y));
          asm("v_cvt_pk_bf16_f32 %0, %1, %2" : "=v"(w3) : "v"(hi[k].z), "v"(hi[k].w));
          u32x4 pw = {w0, w1, w2, w3};
          afr[k] = __builtin_bit_cast(bf16x8, pw);
        }
      }
      __builtin_amdgcn_s_setprio(1);
#pragma unroll
      for (int k = 0; k < 4; ++k)
#pragma unroll
        for (int ni = 0; ni < 4; ++ni)
          acc[4 + k][ni] = __builtin_amdgcn_mfma_f32_16x16x32_bf16(afr[k], bfr[ni], acc[4 + k][ni], 0, 0, 0);
      __builtin_amdgcn_s_setprio(0);
      // per-tile gate: next tile landed; deeper prefetches stay in flight
      if constexpr (AF32) {
        if (t <= NT - 3)      asm volatile("s_waitcnt vmcnt(6)" ::: "memory");
        else if (t == NT - 2) asm volatile("s_waitcnt vmcnt(0)" ::: "memory");
      } else {
        if (t <= NT - 4)      asm volatile("s_waitcnt vmcnt(8)" ::: "memory");
        else if (t == NT - 3) asm volatile("s_waitcnt vmcnt(4)" ::: "memory");
        else if (t == NT - 2) asm volatile("s_waitcnt vmcnt(0)" ::: "memory");
      }
      __builtin_amdgcn_s_barrier();
      __builtin_amdgcn_sched_barrier(0);
    }
  }

  // ---- epilogue: C/D col=lr, row=lq*4+i ----
#pragma unroll
  for (int ni = 0; ni < 4; ++ni) {
    const int gc = n0 + wn * 64 + ni * 16 + lr;
#pragma unroll
    for (int mi = 0; mi < 8; ++mi) {
      const int gr = m0 + wm * 128 + mi * 16 + lq * 4;
      const f32x4 v = acc[mi][ni];
#pragma unroll
      for (int i = 0; i < 4; ++i) {
        const float val = v[i] + bv[ni];
        if constexpr (AF32)
          ((unsigned short*)Cp)[(size_t)(gr + i) * 512 + gc] = f2bf(val > 0.f ? val : 0.f);
        else
          ((float*)Cp)[(size_t)(gr + i) * 512 + gc] = val;
      }
    }
  }
}

// ---------------------------------------------------------------------------
extern "C" void kernel_launch(void* const* d_in, const int* in_sizes, int n_in,
                              void* d_out, int out_size, void* d_ws, size_t ws_size,
                              hipStream_t stream) {
  (void)in_sizes; (void)n_in; (void)out_size; (void)ws_size;
  const float* x  = (const float*)d_in[0];  // (65536, 512)
  const float* G  = (const float*)d_in[1];  // (512, 4)
  const float* H  = (const float*)d_in[2];  // (512, 4)
  const float* b1 = (const float*)d_in[3];  // (512,)
  const float* W2 = (const float*)d_in[4];  // (512, 512)
  const float* b2 = (const float*)d_in[5];  // (512,)
  float* out = (float*)d_out;               // (65536, 512) f32

  char* ws = (char*)d_ws;                                    // ~72.4 MB
  unsigned short* h   = (unsigned short*)ws;                 // 67,108,864 B
  unsigned short* Wt  = (unsigned short*)(ws + 67108864);    //    524,288 B
  unsigned short* W2t = (unsigned short*)(ws + 67633152);    //    524,288 B
  float*          Wp  = (float*)(ws + 68157440);             //  4,194,304 B

  build_w_partials<<<256, 256, 0, stream>>>(G, H, Wp);
  reduce_transpose_w<<<1024, 256, 0, stream>>>(Wp, Wt);
  transpose_convert_w2<<<1024, 256, 0, stream>>>(W2, W2t);
  gemm_pipe<true><<<512, 512, 0, stream>>>((const void*)x, Wt, b1, (void*)h);
  gemm_pipe<false><<<512, 512, 0, stream>>>((const void*)h, W2t, b2, (void*)out);
}